// Round 6
// baseline (180.931 us; speedup 1.0000x reference)
//
#include <hip/hip_runtime.h>

// LeNet-5 forward, fully fused, ONE WAVE PER IMAGE (64-thread blocks).
// conv1(fp32 VALU) -> conv2(bf16 MFMA) -> conv3(bf16 MFMA) -> fc(fp32 VALU).
//
// Bank-conflict-free LDS layouts (the round-5 fix):
//   MFMA A-frag reads are 64-lane b64-pairs at dword D = 6x + (R/2)y + 4q;
//   bank-pair p = 3x + (R/4)y + 2q mod 16. Choosing R = 248 elems makes
//   {3x + 14y mod 16} all-distinct within every 16-row M-tile -> every bank
//   pair gets exactly 4 lanes = 4-cycle minimum, zero conflict cycles.
//   Same for conv3 with h2 pixel-row stride 248 (v = 62 === 14 mod 16).
//   Row pad regions are zeroed (NaN safety); pad VALUES hit zero weights.
//
//   h1: bf16 19 rows x 248 elems ([x*12+c], pads [228,248) zeroed)
//   h2: bf16 10 rows x 248 elems ([x*20+c], pads [200,248) zeroed)

typedef short s16x4 __attribute__((ext_vector_type(4)));
typedef short s16x8 __attribute__((ext_vector_type(8)));
typedef float f32x4 __attribute__((ext_vector_type(4)));

#define ROW1 248            // h1 row stride (elems); 248 % 64 == 56 -> u=14
#define H1_BYTES (19 * ROW1 * 2)        // 9424
#define ROW2 248            // h2 pixel-row stride (elems)
#define SM_SHARED_OFF H1_BYTES          // x / h2s / h3s overlay region
#define SM_BYTES (H1_BYTES + 10 * ROW2 * 2)   // 9424 + 4960 = 14384

static __device__ __forceinline__ unsigned short f2bf(float f) {
    union { float f; unsigned int u; } v; v.f = f;
    unsigned int u = v.u;
    unsigned int r = (u + 0x7fffu + ((u >> 16) & 1u)) >> 16;   // RNE
    return (unsigned short)r;
}

// ---- weight prep ----------------------------------------------------------
// wbuf ushort: [0,40960) conv2 B-frags, [40960,61440) conv3 B-frags,
//              [61440,+2000) w1p as 1000 fp32 (o-pairs adjacent).
// conv2: k=ck*32+quad*8+t, j=k/12, c=k%12  (K-pad in weights = zeros)
// conv3: k=ck*32+quad*8+t, j=k/20, c=k%20
__global__ __launch_bounds__(256) void wprep_k(const float* __restrict__ w2,
                                               const float* __restrict__ w3,
                                               const float* __restrict__ w1,
                                               unsigned short* __restrict__ wbuf) {
    int e = blockIdx.x * 256 + threadIdx.x;
    if (e < 40960) {
        int t = e & 7, lane = (e >> 3) & 63, nt = (e >> 9) & 1;
        int ck = (e >> 10) & 3, i = e >> 12;
        int k = ck * 32 + ((lane >> 4) & 3) * 8 + t;
        int o = nt * 16 + (lane & 15);
        int j = k / 12, c = k % 12;
        float val = (j < 10 && c < 10 && o < 20) ? w2[o * 1000 + c * 100 + i * 10 + j] : 0.f;
        wbuf[e] = f2bf(val);
    } else if (e < 61440) {
        int e2 = e - 40960;
        int t = e2 & 7, lane = (e2 >> 3) & 63, nt = (e2 >> 9) & 1;
        int ck = (e2 >> 10) & 3, i = e2 >> 12;
        int k = ck * 32 + ((lane >> 4) & 3) * 8 + t;
        int o = nt * 16 + (lane & 15);
        int j = k / 20, c = k % 20;
        float val = (j < 5 && o < 20) ? w3[o * 500 + c * 25 + i * 5 + j] : 0.f;
        wbuf[e] = f2bf(val);
    } else if (e < 62440) {
        int t = e - 61440;                 // t = (i*10+j)*10 + o
        int o = t % 10, ij = t / 10;
        int i = ij / 10, j = ij % 10;
        ((float*)(wbuf + 61440))[t] = w1[o * 100 + i * 10 + j];
    }
}

// --------------------------- the fused kernel ------------------------------
__global__ __launch_bounds__(64, 3) void fused_k(const float* __restrict__ x,
                                                 const float* __restrict__ w1p,
                                                 const float* __restrict__ b1,
                                                 const unsigned short* __restrict__ wbuf2,
                                                 const unsigned short* __restrict__ wbuf3,
                                                 const float* __restrict__ b2,
                                                 const float* __restrict__ b3,
                                                 const float* __restrict__ wf,
                                                 const float* __restrict__ bf,
                                                 float* __restrict__ out) {
    __shared__ __align__(16) unsigned char smem[SM_BYTES];
    unsigned short* h1  = (unsigned short*)smem;                    // 9424 B
    float*          sxf = (float*)(smem + SM_SHARED_OFF);           // x (3136 B)
    unsigned short* h2s = (unsigned short*)(smem + SM_SHARED_OFF);  // 4960 B
    float*          h3s = (float*)(smem + SM_SHARED_OFF);           // 2880 B

    const int lane = threadIdx.x;
    const int b = blockIdx.x;
    const int quad = lane >> 4, lm = lane & 15;

    // ---- stage x (784 fp32, float4) + zero h1 row pads ----
    {
        const float4* src = (const float4*)(x + (size_t)b * 784);
        float4* dst = (float4*)sxf;
        for (int k = lane; k < 196; k += 64) dst[k] = src[k];
    }
    for (int e = lane; e < 380; e += 64) {      // h1 pads [228,248) x 19 rows
        int row = e / 20, col = 228 + e % 20;
        h1[row * ROW1 + col] = 0;
    }
    __syncthreads();

    // ---- conv1 (fp32 VALU, float2-paired): 361 positions ----
    for (int it = 0; it < 6; ++it) {
        int pos = it * 64 + lane;
        if (pos < 361) {
            int oy = pos / 19, ox = pos - oy * 19;
            float2 acc2[5];
#pragma unroll
            for (int p = 0; p < 5; ++p) acc2[p] = make_float2(b1[2 * p], b1[2 * p + 1]);
#pragma unroll 1
            for (int i = 0; i < 10; ++i) {
                float r[10];
#pragma unroll
                for (int j = 0; j < 10; ++j) r[j] = sxf[(oy + i) * 28 + ox + j];
                const float* wbase = w1p + i * 100;
#pragma unroll
                for (int j = 0; j < 10; ++j) {
                    const float2* wp = (const float2*)(wbase + j * 10);
                    float rj = r[j];
#pragma unroll
                    for (int p = 0; p < 5; ++p) {
                        float2 w = wp[p];
                        acc2[p].x = fmaf(rj, w.x, acc2[p].x);
                        acc2[p].y = fmaf(rj, w.y, acc2[p].y);
                    }
                }
            }
            unsigned short v[12];
#pragma unroll
            for (int p = 0; p < 5; ++p) {
                v[2 * p]     = f2bf(fmaxf(acc2[p].x, 0.f));
                v[2 * p + 1] = f2bf(fmaxf(acc2[p].y, 0.f));
            }
            v[10] = 0; v[11] = 0;
            unsigned short* dst = h1 + oy * ROW1 + ox * 12;   // 8B-aligned
            s16x4* d4 = (s16x4*)dst;
            d4[0] = (s16x4){ (short)v[0], (short)v[1], (short)v[2],  (short)v[3]  };
            d4[1] = (s16x4){ (short)v[4], (short)v[5], (short)v[6],  (short)v[7]  };
            d4[2] = (s16x4){ (short)v[8], (short)v[9], (short)v[10], (short)v[11] };
        }
    }
    __syncthreads();   // x dead after this point; shared region becomes h2s

    // ---- zero h2 row pads [200,248) x 10 rows (before conv3 reads them) ----
    for (int e = lane; e < 480; e += 64) {
        int row = e / 48, col = 200 + e % 48;
        h2s[row * ROW2 + col] = 0;
    }

    // ---- conv2 MFMA: M=112(100), N=32(20), K=1280 (real 1000) ----
    int abase[7];
#pragma unroll
    for (int mt = 0; mt < 7; ++mt) {
        int m = mt * 16 + lm;
        if (m > 99) m = 99;                   // pad rows: duplicate, discard
        int y = m / 10, xx = m - 10 * y;
        abase[mt] = y * ROW1 + xx * 12 + quad * 8;
    }
    f32x4 acc[7][2] = {};
#pragma unroll 1
    for (int i = 0; i < 10; ++i) {
        const unsigned short* sbi = h1 + i * ROW1;
        const unsigned short* wbi = wbuf2 + i * 4096 + lane * 8;
#pragma unroll
        for (int ck = 0; ck < 4; ++ck) {
            s16x8 wf0 = *(const s16x8*)(wbi + (ck * 2 + 0) * 512);
            s16x8 wf1 = *(const s16x8*)(wbi + (ck * 2 + 1) * 512);
            s16x8 af[7];
#pragma unroll
            for (int mt = 0; mt < 7; ++mt) {
                const unsigned short* p = sbi + abase[mt] + ck * 32;
                s16x4 lo = *(const s16x4*)(p);
                s16x4 hi = *(const s16x4*)(p + 4);
                af[mt] = __builtin_shufflevector(lo, hi, 0, 1, 2, 3, 4, 5, 6, 7);
            }
#pragma unroll
            for (int mt = 0; mt < 7; ++mt) {
                acc[mt][0] = __builtin_amdgcn_mfma_f32_16x16x32_bf16(af[mt], wf0, acc[mt][0], 0, 0, 0);
                acc[mt][1] = __builtin_amdgcn_mfma_f32_16x16x32_bf16(af[mt], wf1, acc[mt][1], 0, 0, 0);
            }
        }
    }
    __syncthreads();

    // ---- scatter conv2 -> h2s rows of 248 ([x*20+c]) ----
#pragma unroll
    for (int nt = 0; nt < 2; ++nt) {
        int o = nt * 16 + lm;
        if (o < 20) {
            float bias = b2[o];
#pragma unroll
            for (int mt = 0; mt < 7; ++mt) {
#pragma unroll
                for (int r = 0; r < 4; ++r) {
                    int pos = mt * 16 + quad * 4 + r;
                    if (pos < 100) {
                        int y2 = pos / 10, x2 = pos - 10 * y2;
                        h2s[y2 * ROW2 + x2 * 20 + o] = f2bf(fmaxf(acc[mt][nt][r] + bias, 0.f));
                    }
                }
            }
        }
    }
    __syncthreads();

    // ---- conv3 MFMA: M=48(36), N=32(20), K=640 (real 500) ----
    int abase3[3];
#pragma unroll
    for (int mt = 0; mt < 3; ++mt) {
        int m = mt * 16 + lm;
        if (m > 35) m = 35;
        int oy = m / 6, ox = m - 6 * oy;
        abase3[mt] = oy * ROW2 + ox * 20 + quad * 8;
    }
    f32x4 acc3[3][2] = {};
#pragma unroll 1
    for (int i = 0; i < 5; ++i) {
        const unsigned short* sbi = h2s + i * ROW2;
        const unsigned short* wbi = wbuf3 + i * 4096 + lane * 8;
#pragma unroll
        for (int ck = 0; ck < 4; ++ck) {
            s16x8 w0 = *(const s16x8*)(wbi + (ck * 2 + 0) * 512);
            s16x8 w1 = *(const s16x8*)(wbi + (ck * 2 + 1) * 512);
            s16x8 af[3];
#pragma unroll
            for (int mt = 0; mt < 3; ++mt) {
                const unsigned short* p = sbi + abase3[mt] + ck * 32;
                s16x4 lo = *(const s16x4*)(p);
                s16x4 hi = *(const s16x4*)(p + 4);
                af[mt] = __builtin_shufflevector(lo, hi, 0, 1, 2, 3, 4, 5, 6, 7);
            }
#pragma unroll
            for (int mt = 0; mt < 3; ++mt) {
                acc3[mt][0] = __builtin_amdgcn_mfma_f32_16x16x32_bf16(af[mt], w0, acc3[mt][0], 0, 0, 0);
                acc3[mt][1] = __builtin_amdgcn_mfma_f32_16x16x32_bf16(af[mt], w1, acc3[mt][1], 0, 0, 0);
            }
        }
    }
    __syncthreads();   // h2s reads done; region becomes h3s

    // ---- conv3 epilogue -> linear h3s[o*36+pos] (fp32, relu) ----
#pragma unroll
    for (int nt = 0; nt < 2; ++nt) {
        int o = nt * 16 + lm;
        if (o < 20) {
            float b3v = b3[o];
#pragma unroll
            for (int mt = 0; mt < 3; ++mt) {
#pragma unroll
                for (int r = 0; r < 4; ++r) {
                    int pos = mt * 16 + quad * 4 + r;
                    if (pos < 36)
                        h3s[o * 36 + pos] = fmaxf(acc3[mt][nt][r] + b3v, 0.f);
                }
            }
        }
    }
    __syncthreads();

    // ---- fc: coalesced global wf (L1-resident), lane l handles k=l+64s ----
    float part[10];
#pragma unroll
    for (int n = 0; n < 10; ++n) part[n] = 0.f;
#pragma unroll 1
    for (int s = 0; s < 12; ++s) {
        int k = s * 64 + lane;
        if (k < 720) {
            float v = h3s[k];
#pragma unroll
            for (int n = 0; n < 10; ++n)
                part[n] = fmaf(v, wf[n * 720 + k], part[n]);
        }
    }
#pragma unroll
    for (int n = 0; n < 10; ++n) {
#pragma unroll
        for (int off = 32; off >= 1; off >>= 1)
            part[n] += __shfl_xor(part[n], off, 64);
    }
    if (lane == 0) {
        float* op = out + (size_t)b * 10;
#pragma unroll
        for (int n = 0; n < 10; ++n) op[n] = part[n] + bf[n];
    }
}

extern "C" void kernel_launch(void* const* d_in, const int* in_sizes, int n_in,
                              void* d_out, int out_size, void* d_ws, size_t ws_size,
                              hipStream_t stream) {
    (void)n_in; (void)out_size; (void)ws_size;
    const float* x  = (const float*)d_in[0];
    const float* w1 = (const float*)d_in[1];
    const float* b1 = (const float*)d_in[2];
    const float* w2 = (const float*)d_in[3];
    const float* b2 = (const float*)d_in[4];
    const float* w3 = (const float*)d_in[5];
    const float* b3 = (const float*)d_in[6];
    const float* wf = (const float*)d_in[7];
    const float* bf = (const float*)d_in[8];
    float* out = (float*)d_out;

    const int B = in_sizes[0] / 784;                       // 4096

    unsigned short* wbuf = (unsigned short*)d_ws;          // ~127 KB
    const float* w1p = (const float*)(wbuf + 61440);

    wprep_k<<<244, 256, 0, stream>>>(w2, w3, w1, wbuf);
    fused_k<<<B, 64, 0, stream>>>(x, w1p, b1, wbuf, wbuf + 40960,
                                  b2, b3, wf, bf, out);
}

// Round 7
// 157.801 us; speedup vs baseline: 1.1466x; 1.1466x over previous
//
#include <hip/hip_runtime.h>

// LeNet-5 forward, fully fused, ONE WAVE PER IMAGE (64-thread blocks).
// ALL three convs on bf16 MFMA (16x16x32); only epilogues + fc on VALU.
//
// conv1 as GEMM (row-only im2col): C[oy][(ox,o)] = sum_k A[oy][k] B[k][(ox,o)]
//   A[m][k] = xflat[m*28 + k]  (sliding flat window -> contiguous LDS reads,
//   8B-aligned, bank-conflict-free). B = banded weights, pre-packed with all
//   zero-padding baked in (wband: K=288, N=192; n=(ox*10+o), k=(i*28+xc),
//   val = w1[o][i][xc-ox] inside the band, else 0).
// conv2/conv3: NHWC exact-C activations, K-pad in weights (as round 5/6),
//   row strides 248 (bank-pair coefficient 14 -> conflict-free M-tiles).
//
// LDS (11024 B -> 14 blocks/CU):
//   [0, 9424)   h1 bf16 19x248     (later overlaid by h2s 4960 B, then h3s)
//   [9424,11024) xbf bf16 800      (x as bf16 + zero tail)

typedef short s16x4 __attribute__((ext_vector_type(4)));
typedef short s16x8 __attribute__((ext_vector_type(8)));
typedef float f32x4 __attribute__((ext_vector_type(4)));

#define ROW1 248
#define ROW2 248
#define XOFF 4712           // xbf elem offset (= 19*248)
#define SM_BYTES 11024

static __device__ __forceinline__ unsigned short f2bf(float f) {
    union { float f; unsigned int u; } v; v.f = f;
    unsigned int u = v.u;
    unsigned int r = (u + 0x7fffu + ((u >> 16) & 1u)) >> 16;   // RNE
    return (unsigned short)r;
}

static __device__ __forceinline__ s16x8 cat8(s16x4 lo, s16x4 hi) {
    return __builtin_shufflevector(lo, hi, 0, 1, 2, 3, 4, 5, 6, 7);
}

// ---- weight prep ----------------------------------------------------------
// wbuf ushort: [0,40960) conv2 B-frags, [40960,61440) conv3 B-frags,
//              [61440,116736) conv1 banded B-frags (wband).
// All use the 16x16x32 B-frag convention: n = nt*16 + (lane&15),
// k = kc*32 + ((lane>>4)&3)*8 + t.
__global__ __launch_bounds__(256) void wprep_k(const float* __restrict__ w1,
                                               const float* __restrict__ w2,
                                               const float* __restrict__ w3,
                                               unsigned short* __restrict__ wbuf) {
    int e = blockIdx.x * 256 + threadIdx.x;
    if (e < 40960) {                       // conv2: j=k/12, c=k%12
        int t = e & 7, lane = (e >> 3) & 63, nt = (e >> 9) & 1;
        int ck = (e >> 10) & 3, i = e >> 12;
        int k = ck * 32 + ((lane >> 4) & 3) * 8 + t;
        int o = nt * 16 + (lane & 15);
        int j = k / 12, c = k % 12;
        float val = (j < 10 && c < 10 && o < 20) ? w2[o * 1000 + c * 100 + i * 10 + j] : 0.f;
        wbuf[e] = f2bf(val);
    } else if (e < 61440) {                // conv3: j=k/20, c=k%20
        int e2 = e - 40960;
        int t = e2 & 7, lane = (e2 >> 3) & 63, nt = (e2 >> 9) & 1;
        int ck = (e2 >> 10) & 3, i = e2 >> 12;
        int k = ck * 32 + ((lane >> 4) & 3) * 8 + t;
        int o = nt * 16 + (lane & 15);
        int j = k / 20, c = k % 20;
        float val = (j < 5 && o < 20) ? w3[o * 500 + c * 25 + i * 5 + j] : 0.f;
        wbuf[e] = f2bf(val);
    } else {                               // conv1 band: [nt(12)][kc(9)][lane][t]
        int e2 = e - 61440;                // < 55296
        int t = e2 & 7, lane = (e2 >> 3) & 63;
        int kc = (e2 >> 9) % 9, nt = (e2 >> 9) / 9;
        int n = nt * 16 + (lane & 15);
        int k = kc * 32 + ((lane >> 4) & 3) * 8 + t;
        float val = 0.f;
        if (n < 190 && k < 280) {
            int ox = n / 10, o = n - ox * 10;
            int i = k / 28, xc = k - i * 28;
            int j = xc - ox;
            if (j >= 0 && j < 10) val = w1[o * 100 + i * 10 + j];
        }
        wbuf[61440 + e2] = f2bf(val);
    }
}

// --------------------------- the fused kernel ------------------------------
__global__ __launch_bounds__(64, 4) void fused_k(const float* __restrict__ x,
                                                 const float* __restrict__ b1,
                                                 const unsigned short* __restrict__ wbuf2,
                                                 const unsigned short* __restrict__ wbuf3,
                                                 const unsigned short* __restrict__ wband,
                                                 const float* __restrict__ b2,
                                                 const float* __restrict__ b3,
                                                 const float* __restrict__ wf,
                                                 const float* __restrict__ bf,
                                                 float* __restrict__ out) {
    __shared__ __align__(16) unsigned char smem[SM_BYTES];
    unsigned short* sm16 = (unsigned short*)smem;
    unsigned short* h1  = sm16;                 // [0, 4712) elems
    unsigned short* xbf = sm16 + XOFF;          // [4712, 5512) elems
    unsigned short* h2s = sm16;                 // later: [0, 2480) elems
    float*          h3s = (float*)smem;         // later: [0, 720) floats

    const int lane = threadIdx.x;
    const int b = blockIdx.x;
    const int quad = lane >> 4, lm = lane & 15;

    // ---- phase 1: stage x as bf16; zero xbf tail, h1 row-pads & c-pads ----
    {
        const float4* src = (const float4*)(x + (size_t)b * 784);
        for (int k = lane; k < 196; k += 64) {
            float4 v = src[k];
            s16x4 p = { (short)f2bf(v.x), (short)f2bf(v.y),
                        (short)f2bf(v.z), (short)f2bf(v.w) };
            *(s16x4*)(xbf + k * 4) = p;
        }
        if (lane < 16) xbf[784 + lane] = 0;
        for (int e = lane; e < 95; e += 64) {          // row pads [228,248) x 19
            int row = e / 5, seg = e - row * 5;
            *(s16x4*)(h1 + row * ROW1 + 228 + seg * 4) = (s16x4){0, 0, 0, 0};
        }
        for (int e = lane; e < 361; e += 64) {         // c-pads (oy,ox,[10,12))
            int oy = e / 19, ox = e - oy * 19;
            *(unsigned int*)(h1 + oy * ROW1 + ox * 12 + 10) = 0u;
        }
    }
    __syncthreads();

    // ---- phase 2: conv1 MFMA  M=32(19), N=192(190), K=288(280) ----
    {
        int m1 = lm + 16; if (m1 > 18) m1 = 18;        // clamp pad rows
        const unsigned short* ab0 = xbf + lm * 28 + quad * 8;
        const unsigned short* ab1 = xbf + m1 * 28 + quad * 8;
        const unsigned short* wb = wband + lane * 8;
#pragma unroll 1
        for (int ntg = 0; ntg < 4; ++ntg) {
            f32x4 acc1[3][2] = {};
#pragma unroll
            for (int kc = 0; kc < 9; ++kc) {
                s16x8 a0 = cat8(*(const s16x4*)(ab0 + kc * 32),
                                *(const s16x4*)(ab0 + kc * 32 + 4));
                s16x8 a1 = cat8(*(const s16x4*)(ab1 + kc * 32),
                                *(const s16x4*)(ab1 + kc * 32 + 4));
#pragma unroll
                for (int q3 = 0; q3 < 3; ++q3) {
                    int nt = ntg * 3 + q3;
                    s16x8 bw = *(const s16x8*)(wb + (nt * 9 + kc) * 512);
                    acc1[q3][0] = __builtin_amdgcn_mfma_f32_16x16x32_bf16(a0, bw, acc1[q3][0], 0, 0, 0);
                    acc1[q3][1] = __builtin_amdgcn_mfma_f32_16x16x32_bf16(a1, bw, acc1[q3][1], 0, 0, 0);
                }
            }
#pragma unroll
            for (int q3 = 0; q3 < 3; ++q3) {
                int n = (ntg * 3 + q3) * 16 + lm;
                if (n < 190) {
                    int ox = n / 10, o = n - ox * 10;
                    float bias = b1[o];
#pragma unroll
                    for (int mt = 0; mt < 2; ++mt) {
#pragma unroll
                        for (int r = 0; r < 4; ++r) {
                            int oy = mt * 16 + quad * 4 + r;
                            if (oy < 19)
                                h1[oy * ROW1 + ox * 12 + o] =
                                    f2bf(fmaxf(acc1[q3][mt][r] + bias, 0.f));
                        }
                    }
                }
            }
        }
    }
    __syncthreads();

    // ---- phase 3: conv2 MFMA  M=112(100), N=32(20), K=1280(1000) ----
    int abase[7];
#pragma unroll
    for (int mt = 0; mt < 7; ++mt) {
        int m = mt * 16 + lm;
        if (m > 99) m = 99;
        int y = m / 10, xx = m - 10 * y;
        abase[mt] = y * ROW1 + xx * 12 + quad * 8;
    }
    f32x4 acc[7][2] = {};
#pragma unroll 1
    for (int i = 0; i < 10; ++i) {
        const unsigned short* sbi = h1 + i * ROW1;
        const unsigned short* wbi = wbuf2 + i * 4096 + lane * 8;
#pragma unroll
        for (int ck = 0; ck < 4; ++ck) {
            s16x8 wf0 = *(const s16x8*)(wbi + (ck * 2 + 0) * 512);
            s16x8 wf1 = *(const s16x8*)(wbi + (ck * 2 + 1) * 512);
            s16x8 af[7];
#pragma unroll
            for (int mt = 0; mt < 7; ++mt) {
                const unsigned short* p = sbi + abase[mt] + ck * 32;
                af[mt] = cat8(*(const s16x4*)(p), *(const s16x4*)(p + 4));
            }
#pragma unroll
            for (int mt = 0; mt < 7; ++mt) {
                acc[mt][0] = __builtin_amdgcn_mfma_f32_16x16x32_bf16(af[mt], wf0, acc[mt][0], 0, 0, 0);
                acc[mt][1] = __builtin_amdgcn_mfma_f32_16x16x32_bf16(af[mt], wf1, acc[mt][1], 0, 0, 0);
            }
        }
    }
    __syncthreads();   // h1 fully consumed; region becomes h2s

    // ---- phase 4: zero h2 row-pads + scatter conv2 -> h2s ([x*20+c]) ----
    for (int e = lane; e < 120; e += 64) {             // pads [200,248) x 10
        int row = e / 12, seg = e - row * 12;
        *(s16x4*)(h2s + row * ROW2 + 200 + seg * 4) = (s16x4){0, 0, 0, 0};
    }
#pragma unroll
    for (int nt = 0; nt < 2; ++nt) {
        int o = nt * 16 + lm;
        if (o < 20) {
            float bias = b2[o];
#pragma unroll
            for (int mt = 0; mt < 7; ++mt) {
#pragma unroll
                for (int r = 0; r < 4; ++r) {
                    int pos = mt * 16 + quad * 4 + r;
                    if (pos < 100) {
                        int y2 = pos / 10, x2 = pos - 10 * y2;
                        h2s[y2 * ROW2 + x2 * 20 + o] = f2bf(fmaxf(acc[mt][nt][r] + bias, 0.f));
                    }
                }
            }
        }
    }
    __syncthreads();

    // ---- phase 5: conv3 MFMA  M=48(36), N=32(20), K=640(500) ----
    int abase3[3];
#pragma unroll
    for (int mt = 0; mt < 3; ++mt) {
        int m = mt * 16 + lm;
        if (m > 35) m = 35;
        int oy = m / 6, ox = m - 6 * oy;
        abase3[mt] = oy * ROW2 + ox * 20 + quad * 8;
    }
    f32x4 acc3[3][2] = {};
#pragma unroll 1
    for (int i = 0; i < 5; ++i) {
        const unsigned short* sbi = h2s + i * ROW2;
        const unsigned short* wbi = wbuf3 + i * 4096 + lane * 8;
#pragma unroll
        for (int ck = 0; ck < 4; ++ck) {
            s16x8 w0 = *(const s16x8*)(wbi + (ck * 2 + 0) * 512);
            s16x8 w1 = *(const s16x8*)(wbi + (ck * 2 + 1) * 512);
            s16x8 af[3];
#pragma unroll
            for (int mt = 0; mt < 3; ++mt) {
                const unsigned short* p = sbi + abase3[mt] + ck * 32;
                af[mt] = cat8(*(const s16x4*)(p), *(const s16x4*)(p + 4));
            }
#pragma unroll
            for (int mt = 0; mt < 3; ++mt) {
                acc3[mt][0] = __builtin_amdgcn_mfma_f32_16x16x32_bf16(af[mt], w0, acc3[mt][0], 0, 0, 0);
                acc3[mt][1] = __builtin_amdgcn_mfma_f32_16x16x32_bf16(af[mt], w1, acc3[mt][1], 0, 0, 0);
            }
        }
    }
    __syncthreads();   // h2s consumed; region becomes h3s

    // ---- phase 6: conv3 epilogue -> linear h3s[o*36+pos] (fp32, relu) ----
#pragma unroll
    for (int nt = 0; nt < 2; ++nt) {
        int o = nt * 16 + lm;
        if (o < 20) {
            float b3v = b3[o];
#pragma unroll
            for (int mt = 0; mt < 3; ++mt) {
#pragma unroll
                for (int r = 0; r < 4; ++r) {
                    int pos = mt * 16 + quad * 4 + r;
                    if (pos < 36)
                        h3s[o * 36 + pos] = fmaxf(acc3[mt][nt][r] + b3v, 0.f);
                }
            }
        }
    }
    __syncthreads();

    // ---- phase 7: fc — coalesced global wf, lane l handles k=l+64s ----
    float part[10];
#pragma unroll
    for (int n = 0; n < 10; ++n) part[n] = 0.f;
#pragma unroll 1
    for (int s = 0; s < 12; ++s) {
        int k = s * 64 + lane;
        if (k < 720) {
            float v = h3s[k];
#pragma unroll
            for (int n = 0; n < 10; ++n)
                part[n] = fmaf(v, wf[n * 720 + k], part[n]);
        }
    }
#pragma unroll
    for (int n = 0; n < 10; ++n) {
#pragma unroll
        for (int off = 32; off >= 1; off >>= 1)
            part[n] += __shfl_xor(part[n], off, 64);
    }
    if (lane == 0) {
        float* op = out + (size_t)b * 10;
#pragma unroll
        for (int n = 0; n < 10; ++n) op[n] = part[n] + bf[n];
    }
}

extern "C" void kernel_launch(void* const* d_in, const int* in_sizes, int n_in,
                              void* d_out, int out_size, void* d_ws, size_t ws_size,
                              hipStream_t stream) {
    (void)n_in; (void)out_size; (void)ws_size;
    const float* x  = (const float*)d_in[0];
    const float* w1 = (const float*)d_in[1];
    const float* b1 = (const float*)d_in[2];
    const float* w2 = (const float*)d_in[3];
    const float* b2 = (const float*)d_in[4];
    const float* w3 = (const float*)d_in[5];
    const float* b3 = (const float*)d_in[6];
    const float* wf = (const float*)d_in[7];
    const float* bf = (const float*)d_in[8];
    float* out = (float*)d_out;

    const int B = in_sizes[0] / 784;                   // 4096

    unsigned short* wbuf = (unsigned short*)d_ws;      // 116736 bf16 = 228 KB

    wprep_k<<<456, 256, 0, stream>>>(w1, w2, w3, wbuf);
    fused_k<<<B, 64, 0, stream>>>(x, b1, wbuf, wbuf + 40960, wbuf + 61440,
                                  b2, b3, wf, bf, out);
}